// Round 1
// baseline (381.325 us; speedup 1.0000x reference)
//
#include <hip/hip_runtime.h>
#include <hip/hip_bf16.h>
#include <math.h>

// Problem constants
// B=4, K=4, L=512, H=16, D=64, HID=1024, MAXPOS=512

typedef __attribute__((ext_vector_type(8))) short short8;
typedef __attribute__((ext_vector_type(4))) float f32x4;

#define MFMA_BF16(a,b,c) __builtin_amdgcn_mfma_f32_16x16x32_bf16((a),(b),(c),0,0,0)

static __device__ __forceinline__ unsigned short f2bf(float x) {
    unsigned int u = __builtin_bit_cast(unsigned int, x);
    u += 0x7fffu + ((u >> 16) & 1u);     // round-to-nearest-even
    return (unsigned short)(u >> 16);
}

// ---------------------------------------------------------------- converts
__global__ void cvt4_kernel(const float* __restrict__ in, unsigned short* __restrict__ out, int n4) {
    for (int i = blockIdx.x * 256 + threadIdx.x; i < n4; i += gridDim.x * 256) {
        float4 v = ((const float4*)in)[i];
        ushort4 o;
        o.x = f2bf(v.x); o.y = f2bf(v.y); o.z = f2bf(v.z); o.w = f2bf(v.w);
        ((ushort4*)out)[i] = o;
    }
}

// ---------------------------------------------------------------- GEMM 128x128, BK=32
// C[m,e] = sum_d A[m,d] * W[e,d] (+bias[e]) ; optional scatter-to-heads bf16 out
// or f32 out with residual add. M multiple of 128, N=K=1024.
__global__ __launch_bounds__(256) void gemm128(
    const unsigned short* __restrict__ A,   // [M][1024] bf16
    const unsigned short* __restrict__ W,   // [1024][1024] bf16 (row e, contig d)
    const float* __restrict__ bias,         // [1024]
    const float* __restrict__ resid,        // [M][1024] f32 or null
    unsigned short* __restrict__ outb,      // [M/512][16][512][64] bf16 or null
    float* __restrict__ outf)               // [M][1024] f32 or null
{
    const int m0 = blockIdx.x * 128, n0 = blockIdx.y * 128;
    __shared__ unsigned short As[128][40];
    __shared__ unsigned short Ws[128][40];
    const int t = threadIdx.x, lane = t & 63, w = t >> 6;
    const int wr = w >> 1, wc = w & 1;
    const int c = lane & 15, g = lane >> 4;

    f32x4 acc[4][4];
#pragma unroll
    for (int i = 0; i < 4; i++)
#pragma unroll
        for (int j = 0; j < 4; j++) acc[i][j] = (f32x4)0.f;

    const int sr = t >> 1, so = (t & 1) * 16;
    for (int kt = 0; kt < 1024; kt += 32) {
        const uint4* pa = (const uint4*)&A[(size_t)(m0 + sr) * 1024 + kt + so];
        uint4 va0 = pa[0], va1 = pa[1];
        const uint4* pw = (const uint4*)&W[(size_t)(n0 + sr) * 1024 + kt + so];
        uint4 vw0 = pw[0], vw1 = pw[1];
        __syncthreads();   // protect previous iteration's fragment reads
        *(uint4*)&As[sr][so] = va0; *(uint4*)&As[sr][so + 8] = va1;
        *(uint4*)&Ws[sr][so] = vw0; *(uint4*)&Ws[sr][so + 8] = vw1;
        __syncthreads();
        short8 af[4], bf_[4];
#pragma unroll
        for (int i = 0; i < 4; i++) af[i] = *(const short8*)&As[wr * 64 + i * 16 + c][g * 8];
#pragma unroll
        for (int j = 0; j < 4; j++) bf_[j] = *(const short8*)&Ws[wc * 64 + j * 16 + c][g * 8];
#pragma unroll
        for (int i = 0; i < 4; i++)
#pragma unroll
            for (int j = 0; j < 4; j++)
                acc[i][j] = MFMA_BF16(af[i], bf_[j], acc[i][j]);
    }

    if (outb) {
#pragma unroll
        for (int i = 0; i < 4; i++)
#pragma unroll
            for (int j = 0; j < 4; j++) {
                int e = n0 + wc * 64 + j * 16 + c;
                float bv = bias[e];
                int h = e >> 6, d = e & 63;
#pragma unroll
                for (int ii = 0; ii < 4; ii++) {
                    int m = m0 + wr * 64 + i * 16 + g * 4 + ii;
                    int grp = m >> 9, l = m & 511;
                    outb[(((size_t)grp * 16 + h) * 512 + l) * 64 + d] = f2bf(acc[i][j][ii] + bv);
                }
            }
    } else {
#pragma unroll
        for (int i = 0; i < 4; i++)
#pragma unroll
            for (int j = 0; j < 4; j++) {
                int e = n0 + wc * 64 + j * 16 + c;
                float bv = bias[e];
#pragma unroll
                for (int ii = 0; ii < 4; ii++) {
                    int m = m0 + wr * 64 + i * 16 + g * 4 + ii;
                    outf[(size_t)m * 1024 + e] = acc[i][j][ii] + bv + resid[(size_t)m * 1024 + e];
                }
            }
    }
}

// ---------------------------------------------------------------- attention
// grid (8 ltiles, 16 heads, 16 bk). One WG = 256 thr = 4 waves; wave w owns
// q-rows [w*16, w*16+16). Flash softmax over 8 r-tiles of 64.
// scores[l,r] = (q.k + q.E[l-r+511] + k.E[l-r+511]) / 8 + mask[bk,r]
__global__ __launch_bounds__(256) void attn_kernel(
    const unsigned short* __restrict__ Qb,   // [4][16][512][64]
    const unsigned short* __restrict__ Kb,   // [16][16][512][64]
    const unsigned short* __restrict__ Vb,   // [16][16][512][64]
    const unsigned short* __restrict__ distb,// [1023][64]
    const float* __restrict__ mask,          // [16][512]
    float* __restrict__ ctx)                 // [16][512][1024]
{
    const int lt = blockIdx.x, h = blockIdx.y, bk = blockIdx.z;
    const int l0 = lt * 64;
    const int b = bk >> 2;                   // repeat_interleave(q, 4)

    extern __shared__ unsigned char smem[];
    unsigned short* Qs  = (unsigned short*)smem;   // [64][72]
    unsigned short* Ks  = Qs  + 64 * 72;           // [64][72]
    unsigned short* Vst = Ks  + 64 * 72;           // [64][72]  d-major: Vst[d][r]
    unsigned short* Ds  = Vst + 64 * 72;           // [128][72] dist window
    unsigned short* Ps  = Ds  + 128 * 72;          // [64][72]  probs bf16
    float* QDs = (float*)(Ps + 64 * 72);           // [64][128]
    float* KDs = QDs + 64 * 128;                   // [64][128]

    const int t = threadIdx.x;
    const int lane = t & 63, w = t >> 6;
    const int c = lane & 15, g = lane >> 4;
    const int lbase = w * 16 + g * 4;

    const unsigned short* Qg = Qb + ((size_t)(b  * 16 + h) * 512) * 64;
    const unsigned short* Kg = Kb + ((size_t)(bk * 16 + h) * 512) * 64;
    const unsigned short* Vg = Vb + ((size_t)(bk * 16 + h) * 512) * 64;

    {   // stage Q tile
        int r = t >> 2, o = (t & 3) * 16;
        const uint4* src = (const uint4*)&Qg[(size_t)(l0 + r) * 64 + o];
        uint4 q0 = src[0], q1 = src[1];
        *(uint4*)&Qs[r * 72 + o] = q0;
        *(uint4*)&Qs[r * 72 + o + 8] = q1;
    }

    float m_run[4], s_run[4];
    f32x4 acc_o[4];
#pragma unroll
    for (int i = 0; i < 4; i++) { m_run[i] = -3.0e38f; s_run[i] = 0.f; acc_o[i] = (f32x4)0.f; }

    for (int r0 = 0; r0 < 512; r0 += 64) {
        {   // stage K, V^T, dist window
            int r = t >> 2, o = (t & 3) * 16;
            const uint4* ksrc = (const uint4*)&Kg[(size_t)(r0 + r) * 64 + o];
            uint4 k0v = ksrc[0], k1v = ksrc[1];
            *(uint4*)&Ks[r * 72 + o] = k0v;
            *(uint4*)&Ks[r * 72 + o + 8] = k1v;
            const uint4* vsrc = (const uint4*)&Vg[(size_t)(r0 + r) * 64 + o];
            uint4 v0 = vsrc[0], v1 = vsrc[1];
            const unsigned short* pv0 = (const unsigned short*)&v0;
            const unsigned short* pv1 = (const unsigned short*)&v1;
#pragma unroll
            for (int j = 0; j < 8; j++) Vst[(o + j) * 72 + r] = pv0[j];
#pragma unroll
            for (int j = 0; j < 8; j++) Vst[(o + 8 + j) * 72 + r] = pv1[j];
            int pbase = l0 - r0 + 448;              // window start, in [0, 896]
            int dr = t >> 1, doff = (t & 1) * 32;
            int p = pbase + dr; p = (p > 1022) ? 1022 : p;   // row 127 can clamp (never read)
            const uint4* dsrc = (const uint4*)&distb[(size_t)p * 64 + doff];
            uint4 d0 = dsrc[0], d1 = dsrc[1], d2 = dsrc[2], d3 = dsrc[3];
            *(uint4*)&Ds[dr * 72 + doff]      = d0;
            *(uint4*)&Ds[dr * 72 + doff + 8]  = d1;
            *(uint4*)&Ds[dr * 72 + doff + 16] = d2;
            *(uint4*)&Ds[dr * 72 + doff + 24] = d3;
        }
        __syncthreads();

        // S1 = Q K^T   (wave's 16 l-rows x 64 r)
        f32x4 s_acc[4];
#pragma unroll
        for (int f = 0; f < 4; f++) s_acc[f] = (f32x4)0.f;
#pragma unroll
        for (int k0 = 0; k0 < 64; k0 += 32) {
            short8 aq = *(const short8*)&Qs[(w * 16 + c) * 72 + k0 + g * 8];
#pragma unroll
            for (int f = 0; f < 4; f++) {
                short8 bkk = *(const short8*)&Ks[(f * 16 + c) * 72 + k0 + g * 8];
                s_acc[f] = MFMA_BF16(aq, bkk, s_acc[f]);
            }
        }
        // QD = Q E^T, KD = K E^T over the 127-wide dist window
#pragma unroll
        for (int pf = 0; pf < 8; pf++) {
            f32x4 aQ = (f32x4)0.f, aK = (f32x4)0.f;
#pragma unroll
            for (int k0 = 0; k0 < 64; k0 += 32) {
                short8 dd = *(const short8*)&Ds[(pf * 16 + c) * 72 + k0 + g * 8];
                short8 aq = *(const short8*)&Qs[(w * 16 + c) * 72 + k0 + g * 8];
                short8 ak = *(const short8*)&Ks[(w * 16 + c) * 72 + k0 + g * 8];
                aQ = MFMA_BF16(aq, dd, aQ);
                aK = MFMA_BF16(ak, dd, aK);
            }
#pragma unroll
            for (int i = 0; i < 4; i++) {
                QDs[(lbase + i) * 128 + pf * 16 + c] = aQ[i];
                KDs[(lbase + i) * 128 + pf * 16 + c] = aK[i];
            }
        }
        __syncthreads();

        // assemble + flash update
        const float* maskrow = mask + (size_t)bk * 512 + r0;
        float pvals[4][4];
        float rmax[4];
#pragma unroll
        for (int i = 0; i < 4; i++) rmax[i] = -3.0e38f;
#pragma unroll
        for (int f = 0; f < 4; f++) {
            int rl = f * 16 + c;
            float mv = maskrow[rl];
#pragma unroll
            for (int i = 0; i < 4; i++) {
                int ll = lbase + i;
                int idx = ll - rl + 63;              // in [0,126]
                float sc = (s_acc[f][i] + QDs[ll * 128 + idx] + KDs[rl * 128 + idx]) * 0.125f + mv;
                pvals[f][i] = sc;
                rmax[i] = fmaxf(rmax[i], sc);
            }
        }
#pragma unroll
        for (int off = 1; off < 16; off <<= 1)
#pragma unroll
            for (int i = 0; i < 4; i++) rmax[i] = fmaxf(rmax[i], __shfl_xor(rmax[i], off));
        float scl[4], rsum[4];
#pragma unroll
        for (int i = 0; i < 4; i++) {
            float mnew = fmaxf(m_run[i], rmax[i]);
            scl[i] = __expf(m_run[i] - mnew);
            m_run[i] = mnew;
            rsum[i] = 0.f;
        }
#pragma unroll
        for (int f = 0; f < 4; f++)
#pragma unroll
            for (int i = 0; i < 4; i++) {
                float pe = __expf(pvals[f][i] - m_run[i]);
                pvals[f][i] = pe;
                rsum[i] += pe;
            }
#pragma unroll
        for (int off = 1; off < 16; off <<= 1)
#pragma unroll
            for (int i = 0; i < 4; i++) rsum[i] += __shfl_xor(rsum[i], off);
#pragma unroll
        for (int i = 0; i < 4; i++) s_run[i] = s_run[i] * scl[i] + rsum[i];
#pragma unroll
        for (int n = 0; n < 4; n++)
#pragma unroll
            for (int i = 0; i < 4; i++) acc_o[n][i] *= scl[i];
#pragma unroll
        for (int f = 0; f < 4; f++)
#pragma unroll
            for (int i = 0; i < 4; i++)
                Ps[(lbase + i) * 72 + f * 16 + c] = f2bf(pvals[f][i]);
        __syncthreads();

        // O += P V
#pragma unroll
        for (int k0 = 0; k0 < 64; k0 += 32) {
            short8 ap = *(const short8*)&Ps[(w * 16 + c) * 72 + k0 + g * 8];
#pragma unroll
            for (int n = 0; n < 4; n++) {
                short8 bv = *(const short8*)&Vst[(n * 16 + c) * 72 + k0 + g * 8];
                acc_o[n] = MFMA_BF16(ap, bv, acc_o[n]);
            }
        }
        __syncthreads();   // protect LDS before next staging
    }

    // finalize: ctx[bk][l][h*64+d] = O/s
#pragma unroll
    for (int i = 0; i < 4; i++) {
        float inv = 1.0f / s_run[i];
        int ll = lbase + i;
        float* dst = ctx + ((size_t)bk * 512 + l0 + ll) * 1024 + h * 64;
#pragma unroll
        for (int n = 0; n < 4; n++) dst[n * 16 + c] = acc_o[n][i] * inv;
    }
}

// ---------------------------------------------------------------- average over k
__global__ void avg_kernel(const float* __restrict__ ctx, unsigned short* __restrict__ avgb) {
    int i = blockIdx.x * 256 + threadIdx.x;     // over 2048*1024/4 float4s
    if (i >= 2048 * 256) return;
    int e4 = i & 255, bl = i >> 8;
    int b = bl >> 9, l = bl & 511;
    const float4* cv = (const float4*)ctx;
    size_t base = ((size_t)(b * 4) * 512 + l) * 256 + e4;
    float4 s = {0.f, 0.f, 0.f, 0.f};
#pragma unroll
    for (int j = 0; j < 4; j++) {
        float4 v = cv[base + (size_t)j * 512 * 256];
        s.x += v.x; s.y += v.y; s.z += v.z; s.w += v.w;
    }
    ushort4 o;
    o.x = f2bf(s.x * 0.25f); o.y = f2bf(s.y * 0.25f);
    o.z = f2bf(s.z * 0.25f); o.w = f2bf(s.w * 0.25f);
    ((ushort4*)avgb)[i] = o;
}

// ---------------------------------------------------------------- LayerNorm rows of 1024 (in-place)
__global__ __launch_bounds__(256) void ln_kernel(float* __restrict__ x,
                                                 const float* __restrict__ gamma,
                                                 const float* __restrict__ beta) {
    const int row = blockIdx.x, t = threadIdx.x;
    float* xr = x + (size_t)row * 1024;
    float v[4], s = 0.f, sq = 0.f;
#pragma unroll
    for (int j = 0; j < 4; j++) { v[j] = xr[t + j * 256]; s += v[j]; sq += v[j] * v[j]; }
#pragma unroll
    for (int off = 1; off < 64; off <<= 1) { s += __shfl_xor(s, off); sq += __shfl_xor(sq, off); }
    __shared__ float ss[4], ssq[4];
    if ((t & 63) == 0) { ss[t >> 6] = s; ssq[t >> 6] = sq; }
    __syncthreads();
    s = ss[0] + ss[1] + ss[2] + ss[3];
    sq = ssq[0] + ssq[1] + ssq[2] + ssq[3];
    float mu = s * (1.f / 1024.f);
    float var = fmaxf(sq * (1.f / 1024.f) - mu * mu, 0.f);
    float inv = 1.0f / sqrtf(var + 1e-12f);
#pragma unroll
    for (int j = 0; j < 4; j++) {
        int e = t + j * 256;
        xr[e] = gamma[e] * (v[j] - mu) * inv + beta[e];
    }
}

// ---------------------------------------------------------------- launch
extern "C" void kernel_launch(void* const* d_in, const int* in_sizes, int n_in,
                              void* d_out, int out_size, void* d_ws, size_t ws_size,
                              hipStream_t stream) {
    const float* hs    = (const float*)d_in[0];
    const float* inj   = (const float*)d_in[1];
    const float* maskp = (const float*)d_in[2];
    const float* Wq    = (const float*)d_in[3];
    const float* bq    = (const float*)d_in[4];
    const float* Wk    = (const float*)d_in[5];
    const float* bk_   = (const float*)d_in[6];
    const float* Wv    = (const float*)d_in[7];
    const float* bv    = (const float*)d_in[8];
    const float* de    = (const float*)d_in[9];
    const float* Wo    = (const float*)d_in[10];
    const float* bo    = (const float*)d_in[11];
    const float* ln_g  = (const float*)d_in[12];
    const float* ln_b  = (const float*)d_in[13];
    float* out = (float*)d_out;
    (void)in_sizes; (void)n_in; (void)out_size; (void)ws_size;

    unsigned char* p = (unsigned char*)d_ws;
    auto take = [&](size_t bytes) {
        unsigned char* r = p;
        p += (bytes + 255) & ~(size_t)255;
        return r;
    };
    unsigned short* hsb   = (unsigned short*)take(2048ull * 1024 * 2);
    unsigned short* injb  = (unsigned short*)take(8192ull * 1024 * 2);
    unsigned short* Wqb   = (unsigned short*)take(1024ull * 1024 * 2);
    unsigned short* Wkb   = (unsigned short*)take(1024ull * 1024 * 2);
    unsigned short* Wvb   = (unsigned short*)take(1024ull * 1024 * 2);
    unsigned short* Wob   = (unsigned short*)take(1024ull * 1024 * 2);
    unsigned short* distb = (unsigned short*)take(1023ull * 64 * 2);
    unsigned short* Qbuf  = (unsigned short*)take(4ull * 16 * 512 * 64 * 2);
    unsigned short* Kbuf  = (unsigned short*)take(16ull * 16 * 512 * 64 * 2);
    unsigned short* Vbuf  = (unsigned short*)take(16ull * 16 * 512 * 64 * 2);
    float*          ctx   = (float*)take(16ull * 512 * 1024 * 4);
    unsigned short* avgb  = (unsigned short*)take(2048ull * 1024 * 2);

    // f32 -> bf16 converts
    cvt4_kernel<<<2048, 256, 0, stream>>>(hs,  hsb,  2048 * 1024 / 4);
    cvt4_kernel<<<8192, 256, 0, stream>>>(inj, injb, 8192 * 1024 / 4);
    cvt4_kernel<<<1024, 256, 0, stream>>>(Wq,  Wqb,  1024 * 1024 / 4);
    cvt4_kernel<<<1024, 256, 0, stream>>>(Wk,  Wkb,  1024 * 1024 / 4);
    cvt4_kernel<<<1024, 256, 0, stream>>>(Wv,  Wvb,  1024 * 1024 / 4);
    cvt4_kernel<<<1024, 256, 0, stream>>>(Wo,  Wob,  1024 * 1024 / 4);
    cvt4_kernel<<<64,   256, 0, stream>>>(de,  distb, 1023 * 64 / 4);

    // projections
    dim3 gq(16, 8), gkv(64, 8);
    gemm128<<<gq,  256, 0, stream>>>(hsb,  Wqb, bq,  nullptr, Qbuf, nullptr);
    gemm128<<<gkv, 256, 0, stream>>>(injb, Wkb, bk_, nullptr, Kbuf, nullptr);
    gemm128<<<gkv, 256, 0, stream>>>(injb, Wvb, bv,  nullptr, Vbuf, nullptr);

    // attention (dynamic LDS 118 KB)
    hipFuncSetAttribute((const void*)attn_kernel,
                        hipFuncAttributeMaxDynamicSharedMemorySize, 131072);
    dim3 ga(8, 16, 16);
    attn_kernel<<<ga, 256, 120832, stream>>>(Qbuf, Kbuf, Vbuf, distb, maskp, ctx);

    // average over k candidates
    avg_kernel<<<2048, 256, 0, stream>>>(ctx, avgb);

    // output projection + bias + residual, then LayerNorm in-place on d_out
    gemm128<<<gq, 256, 0, stream>>>(avgb, Wob, bo, hs, nullptr, out);
    ln_kernel<<<2048, 256, 0, stream>>>(out, ln_g, ln_b);
}

// Round 2
// 329.060 us; speedup vs baseline: 1.1588x; 1.1588x over previous
//
#include <hip/hip_runtime.h>
#include <hip/hip_bf16.h>
#include <math.h>

// B=4, K=4, L=512, H=16, D=64, HID=1024, MAXPOS=512

typedef __attribute__((ext_vector_type(8))) short short8;
typedef __attribute__((ext_vector_type(4))) float f32x4;

#define MFMA_BF16(a,b,c) __builtin_amdgcn_mfma_f32_16x16x32_bf16((a),(b),(c),0,0,0)
#define GLL16(gp, lp) __builtin_amdgcn_global_load_lds( \
    (const __attribute__((address_space(1))) void*)(gp), \
    (__attribute__((address_space(3))) void*)(lp), 16, 0, 0)

static __device__ __forceinline__ unsigned short f2bf(float x) {
    unsigned int u = __builtin_bit_cast(unsigned int, x);
    u += 0x7fffu + ((u >> 16) & 1u);     // round-to-nearest-even
    return (unsigned short)(u >> 16);
}
static __device__ __forceinline__ float bf2f(unsigned short u) {
    unsigned int v = ((unsigned int)u) << 16;
    return __builtin_bit_cast(float, v);
}

// ---------------------------------------------------------------- fused converts
struct CvtArgs {
    const float* s[7];
    unsigned short* d[7];
    int n4[7];
};
__global__ void cvt_all(CvtArgs a) {
#pragma unroll 1
    for (int k = 0; k < 7; k++) {
        const float4* s = (const float4*)a.s[k];
        ushort4* d = (ushort4*)a.d[k];
        const int n = a.n4[k];
        for (int i = blockIdx.x * 256 + threadIdx.x; i < n; i += gridDim.x * 256) {
            float4 v = s[i];
            ushort4 o;
            o.x = f2bf(v.x); o.y = f2bf(v.y); o.z = f2bf(v.z); o.w = f2bf(v.w);
            d[i] = o;
        }
    }
}

// ---------------------------------------------------------------- GEMM 128x128, BK=32 (m97 structure)
// C[m,e] = sum_d A[m,d]*W[e,d] + bias[e]. Epilogues: outb (bf16 head-scatter),
// outv (bf16 transposed head-scatter [grp][h][d][l]), outf (f32 + resid).
__global__ __launch_bounds__(256) void gemm128(
    const unsigned short* __restrict__ A,
    const unsigned short* __restrict__ W,
    const float* __restrict__ bias,
    const float* __restrict__ resid,
    unsigned short* __restrict__ outb,
    unsigned short* __restrict__ outv,
    float* __restrict__ outf)
{
    const int m0 = blockIdx.x * 128, n0 = blockIdx.y * 128;
    __shared__ unsigned short As[128 * 32];
    __shared__ unsigned short Ws[128 * 32];
    const int t = threadIdx.x, lane = t & 63, w = t >> 6;
    const int wr = w >> 1, wc = w & 1;
    const int c = lane & 15, g = lane >> 4;

    f32x4 acc[4][4];
#pragma unroll
    for (int i = 0; i < 4; i++)
#pragma unroll
        for (int j = 0; j < 4; j++) acc[i][j] = (f32x4)0.f;

    const size_t arow = (size_t)(m0 + (t >> 2)) * 1024 + (size_t)((t & 3) * 8);
    const size_t wrow = (size_t)(n0 + (t >> 2)) * 1024 + (size_t)((t & 3) * 8);
    unsigned short* asd = As + t * 8;
    unsigned short* wsd = Ws + t * 8;

    for (int kt = 0; kt < 1024; kt += 32) {
        __syncthreads();                     // previous iteration's LDS reads done
        GLL16(A + arow + kt, asd);
        GLL16(A + arow + 64 * 1024 + kt, asd + 2048);
        GLL16(W + wrow + kt, wsd);
        GLL16(W + wrow + 64 * 1024 + kt, wsd + 2048);
        __syncthreads();                     // barrier drains vmcnt -> LDS visible
        short8 af[4], bf_[4];
#pragma unroll
        for (int i = 0; i < 4; i++) af[i] = *(const short8*)&As[(wr * 64 + i * 16 + c) * 32 + g * 8];
#pragma unroll
        for (int j = 0; j < 4; j++) bf_[j] = *(const short8*)&Ws[(wc * 64 + j * 16 + c) * 32 + g * 8];
#pragma unroll
        for (int i = 0; i < 4; i++)
#pragma unroll
            for (int j = 0; j < 4; j++)
                acc[i][j] = MFMA_BF16(af[i], bf_[j], acc[i][j]);
    }

    if (outb) {
#pragma unroll
        for (int i = 0; i < 4; i++)
#pragma unroll
            for (int j = 0; j < 4; j++) {
                int e = n0 + wc * 64 + j * 16 + c;
                float bv = bias[e];
                int hh = e >> 6, d = e & 63;
#pragma unroll
                for (int ii = 0; ii < 4; ii++) {
                    int m = m0 + wr * 64 + i * 16 + g * 4 + ii;
                    int grp = m >> 9, l = m & 511;
                    outb[(((size_t)grp * 16 + hh) * 512 + l) * 64 + d] = f2bf(acc[i][j][ii] + bv);
                }
            }
    } else if (outv) {
#pragma unroll
        for (int i = 0; i < 4; i++)
#pragma unroll
            for (int j = 0; j < 4; j++) {
                int e = n0 + wc * 64 + j * 16 + c;
                float bv = bias[e];
                int hh = e >> 6, d = e & 63;
                int mb = m0 + wr * 64 + i * 16 + g * 4;
                int grp = mb >> 9, l = mb & 511;
                ushort4 o;
                o.x = f2bf(acc[i][j][0] + bv);
                o.y = f2bf(acc[i][j][1] + bv);
                o.z = f2bf(acc[i][j][2] + bv);
                o.w = f2bf(acc[i][j][3] + bv);
                *(ushort4*)&outv[(((size_t)grp * 16 + hh) * 64 + d) * 512 + l] = o;
            }
    } else {
#pragma unroll
        for (int i = 0; i < 4; i++)
#pragma unroll
            for (int j = 0; j < 4; j++) {
                int e = n0 + wc * 64 + j * 16 + c;
                float bv = bias[e];
#pragma unroll
                for (int ii = 0; ii < 4; ii++) {
                    int m = m0 + wr * 64 + i * 16 + g * 4 + ii;
                    outf[(size_t)m * 1024 + e] = acc[i][j][ii] + bv + resid[(size_t)m * 1024 + e];
                }
            }
    }
}

// ---------------------------------------------------------------- attention
// grid (8 ltiles, 16 heads, 16 bk); 4 waves, wave w owns q-rows [w*16, w*16+16).
// scores[l,r] = (q.k + q.E[l-r+511] + k.E[l-r+511]) / 8 + mask[bk,r]
// Q frags hoisted to registers; QD/KD bands compact bf16 (5 frags/wave);
// Ps aliased into Ds. LDS = 54272 B -> 3 WG/CU.
__global__ __launch_bounds__(256, 3) void attn_kernel(
    const unsigned short* __restrict__ Qb,   // [4][16][512][64]
    const unsigned short* __restrict__ Kb,   // [16][16][512][64]
    const unsigned short* __restrict__ Vtb,  // [16][16][64][512] (d-major)
    const unsigned short* __restrict__ distb,// [1023][64]
    const float* __restrict__ mask,          // [16][512]
    unsigned short* __restrict__ ctxb)       // [16][512][1024] bf16
{
    const int lt = blockIdx.x, h = blockIdx.y, bk = blockIdx.z;
    const int l0 = lt * 64;
    const int b = bk >> 2;                   // repeat_interleave(q, 4)

    __shared__ unsigned short Ks[64 * 68];
    __shared__ unsigned short Vst[64 * 68];  // d-major: Vst[d][r]
    __shared__ unsigned short Ds[128 * 68];  // dist window; Ps aliases start
    __shared__ unsigned short QDc[64 * 76];  // compact band, bf16
    __shared__ unsigned short KDc[64 * 76];
    unsigned short* Ps = Ds;                 // [64][72] probs, bf16

    const int t = threadIdx.x, lane = t & 63, w = t >> 6;
    const int c = lane & 15, g = lane >> 4;

    const unsigned short* Qg = Qb + ((size_t)(b  * 16 + h) * 512) * 64;
    const unsigned short* Kg = Kb + ((size_t)(bk * 16 + h) * 512) * 64;
    const unsigned short* Vg = Vtb + ((size_t)(bk * 16 + h) * 64) * 512;

    // Q fragments hoisted: reused by S1 and all QD MFMAs, every r-tile
    short8 aq0 = *(const short8*)&Qg[(size_t)(l0 + w * 16 + c) * 64 + g * 8];
    short8 aq1 = *(const short8*)&Qg[(size_t)(l0 + w * 16 + c) * 64 + 32 + g * 8];

    float m_run[4], s_run[4];
    f32x4 acc_o[4];
#pragma unroll
    for (int i = 0; i < 4; i++) { m_run[i] = -3.0e38f; s_run[i] = 0.f; acc_o[i] = (f32x4)0.f; }

    const int sr = t >> 2, so = (t & 3) * 16;   // K/V staging: row, elem offset
    const int dr = t >> 1, doff = (t & 1) * 32; // Ds staging

    for (int r0 = 0; r0 < 512; r0 += 64) {
        // issue global loads into registers (overlap with barrier wait)
        const uint4* ksrc = (const uint4*)&Kg[(size_t)(r0 + sr) * 64 + so];
        uint4 kv0 = ksrc[0], kv1 = ksrc[1];
        const uint4* vsrc = (const uint4*)&Vg[(size_t)sr * 512 + r0 + so];
        uint4 vv0 = vsrc[0], vv1 = vsrc[1];
        const int pbase = l0 - r0 + 448;        // window start in [0, 896]
        int p = pbase + dr; if (p > 1022) p = 1022;  // row 127 may clamp (never read)
        const uint4* dsrc = (const uint4*)&distb[(size_t)p * 64 + doff];
        uint4 dv0 = dsrc[0], dv1 = dsrc[1], dv2 = dsrc[2], dv3 = dsrc[3];

        __syncthreads();                        // (1) prev-iteration LDS reads done
        *(uint4*)&Ks[sr * 68 + so] = kv0;   *(uint4*)&Ks[sr * 68 + so + 8] = kv1;
        *(uint4*)&Vst[sr * 68 + so] = vv0;  *(uint4*)&Vst[sr * 68 + so + 8] = vv1;
        *(uint4*)&Ds[dr * 68 + doff]      = dv0;
        *(uint4*)&Ds[dr * 68 + doff + 8]  = dv1;
        *(uint4*)&Ds[dr * 68 + doff + 16] = dv2;
        *(uint4*)&Ds[dr * 68 + doff + 24] = dv3;
        __syncthreads();                        // (2) staging visible

        // S1 = Q K^T; cache K B-frags (bk0/bk1[w] doubles as KD's A-operand)
        short8 bkf0[4], bkf1[4];
        f32x4 s_acc[4];
#pragma unroll
        for (int f = 0; f < 4; f++) {
            bkf0[f] = *(const short8*)&Ks[(f * 16 + c) * 68 + g * 8];
            bkf1[f] = *(const short8*)&Ks[(f * 16 + c) * 68 + 32 + g * 8];
            f32x4 z = (f32x4)0.f;
            z = MFMA_BF16(aq0, bkf0[f], z);
            s_acc[f] = MFMA_BF16(aq1, bkf1[f], z);
        }
        // QD/KD bands: only the 5 needed p-frags per wave
#pragma unroll
        for (int q5 = 0; q5 < 5; q5++) {
            const int pq = w + q5;              // QD frags [w, w+4]
            short8 dq0 = *(const short8*)&Ds[(pq * 16 + c) * 68 + g * 8];
            short8 dq1 = *(const short8*)&Ds[(pq * 16 + c) * 68 + 32 + g * 8];
            f32x4 aQ = (f32x4)0.f;
            aQ = MFMA_BF16(aq0, dq0, aQ);
            aQ = MFMA_BF16(aq1, dq1, aQ);
            const int pk = (3 - w) + q5;        // KD frags [3-w, 7-w]
            short8 dk0 = *(const short8*)&Ds[(pk * 16 + c) * 68 + g * 8];
            short8 dk1 = *(const short8*)&Ds[(pk * 16 + c) * 68 + 32 + g * 8];
            f32x4 aK = (f32x4)0.f;
            aK = MFMA_BF16(bkf0[w], dk0, aK);
            aK = MFMA_BF16(bkf1[w], dk1, aK);
#pragma unroll
            for (int i = 0; i < 4; i++) {
                QDc[(w * 16 + g * 4 + i) * 76 + q5 * 16 + c] = f2bf(aQ[i]);
                KDc[(w * 16 + g * 4 + i) * 76 + q5 * 16 + c] = f2bf(aK[i]);
            }
        }
        __syncthreads();                        // (3) QDc/KDc visible

        // assemble scores + online softmax
        const float* maskrow = mask + (size_t)bk * 512 + r0;
        float pv[4][4], rmax[4];
#pragma unroll
        for (int i = 0; i < 4; i++) rmax[i] = -3.0e38f;
#pragma unroll
        for (int f = 0; f < 4; f++) {
            int rl = f * 16 + c;
            float mv = maskrow[rl];
#pragma unroll
            for (int i = 0; i < 4; i++) {
                int lloc = g * 4 + i;
                // QDc[ll][lloc - rl + 63], KDc[rl][ll - c + 15]  (compact cols)
                float qd = bf2f(QDc[(w * 16 + lloc) * 76 + (lloc - rl + 63)]);
                float kd = bf2f(KDc[rl * 76 + (w * 16 + lloc - c + 15)]);
                float sc = (s_acc[f][i] + qd + kd) * 0.125f + mv;
                pv[f][i] = sc;
                rmax[i] = fmaxf(rmax[i], sc);
            }
        }
#pragma unroll
        for (int off = 1; off < 16; off <<= 1)
#pragma unroll
            for (int i = 0; i < 4; i++) rmax[i] = fmaxf(rmax[i], __shfl_xor(rmax[i], off));
        float scl[4], rsum[4];
#pragma unroll
        for (int i = 0; i < 4; i++) {
            float mnew = fmaxf(m_run[i], rmax[i]);
            scl[i] = __expf(m_run[i] - mnew);
            m_run[i] = mnew;
            rsum[i] = 0.f;
        }
#pragma unroll
        for (int f = 0; f < 4; f++)
#pragma unroll
            for (int i = 0; i < 4; i++) {
                float pe = __expf(pv[f][i] - m_run[i]);
                pv[f][i] = pe;
                rsum[i] += pe;
            }
#pragma unroll
        for (int off = 1; off < 16; off <<= 1)
#pragma unroll
            for (int i = 0; i < 4; i++) rsum[i] += __shfl_xor(rsum[i], off);
#pragma unroll
        for (int i = 0; i < 4; i++) s_run[i] = s_run[i] * scl[i] + rsum[i];
#pragma unroll
        for (int n = 0; n < 4; n++)
#pragma unroll
            for (int i = 0; i < 4; i++) acc_o[n][i] *= scl[i];
        // P -> LDS (own rows only; no barrier needed before PV)
#pragma unroll
        for (int f = 0; f < 4; f++)
#pragma unroll
            for (int i = 0; i < 4; i++)
                Ps[(w * 16 + g * 4 + i) * 72 + f * 16 + c] = f2bf(pv[f][i]);

        // O += P V
#pragma unroll
        for (int k0 = 0; k0 < 64; k0 += 32) {
            short8 ap = *(const short8*)&Ps[(w * 16 + c) * 72 + k0 + g * 8];
#pragma unroll
            for (int n = 0; n < 4; n++) {
                short8 bv = *(const short8*)&Vst[(n * 16 + c) * 68 + k0 + g * 8];
                acc_o[n] = MFMA_BF16(ap, bv, acc_o[n]);
            }
        }
    }

    // finalize: ctx[bk][l][h*64+d] = O/s  (bf16)
#pragma unroll
    for (int i = 0; i < 4; i++) {
        float inv = 1.0f / s_run[i];
        int ll = w * 16 + g * 4 + i;
        unsigned short* dst = ctxb + ((size_t)bk * 512 + l0 + ll) * 1024 + h * 64;
#pragma unroll
        for (int n = 0; n < 4; n++) dst[n * 16 + c] = f2bf(acc_o[n][i] * inv);
    }
}

// ---------------------------------------------------------------- average over k (bf16)
__global__ void avg_kernel(const unsigned short* __restrict__ ctx, unsigned short* __restrict__ avgb) {
    int i = blockIdx.x * 256 + threadIdx.x;     // ushort4 index over [2048][256]
    if (i >= 2048 * 256) return;
    int e4 = i & 255, bl = i >> 8;
    int b = bl >> 9, l = bl & 511;
    size_t base = ((size_t)(b * 4) * 512 + l) * 256 + e4;
    const ushort4* cv = (const ushort4*)ctx;
    float s0 = 0.f, s1 = 0.f, s2 = 0.f, s3 = 0.f;
#pragma unroll
    for (int j = 0; j < 4; j++) {
        ushort4 v = cv[base + (size_t)j * 512 * 256];
        s0 += bf2f(v.x); s1 += bf2f(v.y); s2 += bf2f(v.z); s3 += bf2f(v.w);
    }
    ushort4 o;
    o.x = f2bf(s0 * 0.25f); o.y = f2bf(s1 * 0.25f);
    o.z = f2bf(s2 * 0.25f); o.w = f2bf(s3 * 0.25f);
    ((ushort4*)avgb)[i] = o;
}

// ---------------------------------------------------------------- LayerNorm rows of 1024 (in-place)
__global__ __launch_bounds__(256) void ln_kernel(float* __restrict__ x,
                                                 const float* __restrict__ gamma,
                                                 const float* __restrict__ beta) {
    const int row = blockIdx.x, t = threadIdx.x;
    float* xr = x + (size_t)row * 1024;
    float v[4], s = 0.f, sq = 0.f;
#pragma unroll
    for (int j = 0; j < 4; j++) { v[j] = xr[t + j * 256]; s += v[j]; sq += v[j] * v[j]; }
#pragma unroll
    for (int off = 1; off < 64; off <<= 1) { s += __shfl_xor(s, off); sq += __shfl_xor(sq, off); }
    __shared__ float ss[4], ssq[4];
    if ((t & 63) == 0) { ss[t >> 6] = s; ssq[t >> 6] = sq; }
    __syncthreads();
    s = ss[0] + ss[1] + ss[2] + ss[3];
    sq = ssq[0] + ssq[1] + ssq[2] + ssq[3];
    float mu = s * (1.f / 1024.f);
    float var = fmaxf(sq * (1.f / 1024.f) - mu * mu, 0.f);
    float inv = 1.0f / sqrtf(var + 1e-12f);
#pragma unroll
    for (int j = 0; j < 4; j++) {
        int e = t + j * 256;
        xr[e] = gamma[e] * (v[j] - mu) * inv + beta[e];
    }
}

// ---------------------------------------------------------------- launch
extern "C" void kernel_launch(void* const* d_in, const int* in_sizes, int n_in,
                              void* d_out, int out_size, void* d_ws, size_t ws_size,
                              hipStream_t stream) {
    const float* hs    = (const float*)d_in[0];
    const float* inj   = (const float*)d_in[1];
    const float* maskp = (const float*)d_in[2];
    const float* Wq    = (const float*)d_in[3];
    const float* bq    = (const float*)d_in[4];
    const float* Wk    = (const float*)d_in[5];
    const float* bk_   = (const float*)d_in[6];
    const float* Wv    = (const float*)d_in[7];
    const float* bv    = (const float*)d_in[8];
    const float* de    = (const float*)d_in[9];
    const float* Wo    = (const float*)d_in[10];
    const float* bo    = (const float*)d_in[11];
    const float* ln_g  = (const float*)d_in[12];
    const float* ln_b  = (const float*)d_in[13];
    float* out = (float*)d_out;
    (void)in_sizes; (void)n_in; (void)out_size; (void)ws_size;

    unsigned char* p = (unsigned char*)d_ws;
    auto take = [&](size_t bytes) {
        unsigned char* r = p;
        p += (bytes + 255) & ~(size_t)255;
        return r;
    };
    unsigned short* hsb   = (unsigned short*)take(2048ull * 1024 * 2);
    unsigned short* injb  = (unsigned short*)take(8192ull * 1024 * 2);
    unsigned short* Wqb   = (unsigned short*)take(1024ull * 1024 * 2);
    unsigned short* Wkb   = (unsigned short*)take(1024ull * 1024 * 2);
    unsigned short* Wvb   = (unsigned short*)take(1024ull * 1024 * 2);
    unsigned short* Wob   = (unsigned short*)take(1024ull * 1024 * 2);
    unsigned short* distb = (unsigned short*)take(1023ull * 64 * 2);
    unsigned short* Qbuf  = (unsigned short*)take(4ull * 16 * 512 * 64 * 2);
    unsigned short* Kbuf  = (unsigned short*)take(16ull * 16 * 512 * 64 * 2);
    unsigned short* Vtb   = (unsigned short*)take(16ull * 16 * 64 * 512 * 2);
    unsigned short* ctxb  = (unsigned short*)take(16ull * 512 * 1024 * 2);
    unsigned short* avgb  = (unsigned short*)take(2048ull * 1024 * 2);

    // fused f32 -> bf16 converts (1 launch)
    CvtArgs ca;
    ca.s[0] = hs;  ca.d[0] = hsb;   ca.n4[0] = 2048 * 256;
    ca.s[1] = inj; ca.d[1] = injb;  ca.n4[1] = 8192 * 256;
    ca.s[2] = Wq;  ca.d[2] = Wqb;   ca.n4[2] = 1024 * 256;
    ca.s[3] = Wk;  ca.d[3] = Wkb;   ca.n4[3] = 1024 * 256;
    ca.s[4] = Wv;  ca.d[4] = Wvb;   ca.n4[4] = 1024 * 256;
    ca.s[5] = Wo;  ca.d[5] = Wob;   ca.n4[5] = 1024 * 256;
    ca.s[6] = de;  ca.d[6] = distb; ca.n4[6] = 1023 * 16;
    cvt_all<<<2048, 256, 0, stream>>>(ca);

    // projections
    dim3 gq(16, 8), gkv(64, 8);
    gemm128<<<gq,  256, 0, stream>>>(hsb,  Wqb, bq,  nullptr, Qbuf, nullptr, nullptr);
    gemm128<<<gkv, 256, 0, stream>>>(injb, Wkb, bk_, nullptr, Kbuf, nullptr, nullptr);
    gemm128<<<gkv, 256, 0, stream>>>(injb, Wvb, bv,  nullptr, nullptr, Vtb, nullptr);

    // attention (static LDS 54272 B -> 3 WG/CU)
    attn_kernel<<<dim3(8, 16, 16), 256, 0, stream>>>(Qbuf, Kbuf, Vtb, distb, maskp, ctxb);

    // average over k candidates
    avg_kernel<<<2048, 256, 0, stream>>>(ctxb, avgb);

    // output projection + bias + residual, then LayerNorm in-place on d_out
    gemm128<<<gq, 256, 0, stream>>>(avgb, Wob, bo, hs, nullptr, nullptr, out);
    ln_kernel<<<2048, 256, 0, stream>>>(out, ln_g, ln_b);
}

// Round 3
// 269.300 us; speedup vs baseline: 1.4160x; 1.2219x over previous
//
#include <hip/hip_runtime.h>
#include <hip/hip_bf16.h>
#include <math.h>

// B=4, K=4, L=512, H=16, D=64, HID=1024, MAXPOS=512

typedef __attribute__((ext_vector_type(8))) short short8;
typedef __attribute__((ext_vector_type(4))) float f32x4;

#define MFMA_BF16(a,b,c) __builtin_amdgcn_mfma_f32_16x16x32_bf16((a),(b),(c),0,0,0)
#define GLL16(gp, lp) __builtin_amdgcn_global_load_lds( \
    (const __attribute__((address_space(1))) void*)(gp), \
    (__attribute__((address_space(3))) void*)(lp), 16, 0, 0)

static __device__ __forceinline__ unsigned short f2bf(float x) {
    unsigned int u = __builtin_bit_cast(unsigned int, x);
    u += 0x7fffu + ((u >> 16) & 1u);     // round-to-nearest-even
    return (unsigned short)(u >> 16);
}
static __device__ __forceinline__ float bf2f(unsigned short u) {
    unsigned int v = ((unsigned int)u) << 16;
    return __builtin_bit_cast(float, v);
}
static __device__ __forceinline__ unsigned cvt_pk_bf16(float lo, float hi) {
    unsigned r;
    asm("v_cvt_pk_bf16_f32 %0, %1, %2" : "=v"(r) : "v"(lo), "v"(hi));
    return r;
}
static __device__ __forceinline__ float exp2_fast(float x) {
    float r;
    asm("v_exp_f32 %0, %1" : "=v"(r) : "v"(x));
    return r;
}

// ---------------------------------------------------------------- fused converts
// entry 6 (dist_emb) is written in XOR-swizzled 16B-unit order:
// global unit u' of row p holds element-unit u'^(p&7).
struct CvtArgs {
    const float* s[7];
    unsigned short* d[7];
    int n4[7];
};
__global__ void cvt_all(CvtArgs a) {
#pragma unroll 1
    for (int k = 0; k < 7; k++) {
        const float4* s = (const float4*)a.s[k];
        ushort4* d = (ushort4*)a.d[k];
        const int n = a.n4[k];
        const bool swz = (k == 6);
        for (int i = blockIdx.x * 256 + threadIdx.x; i < n; i += gridDim.x * 256) {
            float4 v = s[i];
            ushort4 o;
            o.x = f2bf(v.x); o.y = f2bf(v.y); o.z = f2bf(v.z); o.w = f2bf(v.w);
            int di = i;
            if (swz) {
                int p = i >> 4, j = i & 15;
                di = p * 16 + (((j >> 1) ^ (p & 7)) * 2 + (j & 1));
            }
            d[di] = o;
        }
    }
}

// ---------------------------------------------------------------- GEMM 128x128, BK=32 (m97 structure)
// C[m,e] = sum_d A[m,d]*W[e,d] + bias[e].
// Epilogues: outb (bf16 head-scatter, optional K-swizzle), outv (bf16 transposed
// head-scatter [grp][h][d][l]), outf (f32 + resid).
__global__ __launch_bounds__(256) void gemm128(
    const unsigned short* __restrict__ A,
    const unsigned short* __restrict__ W,
    const float* __restrict__ bias,
    const float* __restrict__ resid,
    unsigned short* __restrict__ outb,
    unsigned short* __restrict__ outv,
    float* __restrict__ outf,
    int kswz)
{
    const int m0 = blockIdx.x * 128, n0 = blockIdx.y * 128;
    __shared__ unsigned short As[128 * 32];
    __shared__ unsigned short Ws[128 * 32];
    const int t = threadIdx.x, lane = t & 63, w = t >> 6;
    const int wr = w >> 1, wc = w & 1;
    const int c = lane & 15, g = lane >> 4;

    f32x4 acc[4][4];
#pragma unroll
    for (int i = 0; i < 4; i++)
#pragma unroll
        for (int j = 0; j < 4; j++) acc[i][j] = (f32x4)0.f;

    const size_t arow = (size_t)(m0 + (t >> 2)) * 1024 + (size_t)((t & 3) * 8);
    const size_t wrow = (size_t)(n0 + (t >> 2)) * 1024 + (size_t)((t & 3) * 8);
    unsigned short* asd = As + t * 8;
    unsigned short* wsd = Ws + t * 8;

    for (int kt = 0; kt < 1024; kt += 32) {
        __syncthreads();
        GLL16(A + arow + kt, asd);
        GLL16(A + arow + 64 * 1024 + kt, asd + 2048);
        GLL16(W + wrow + kt, wsd);
        GLL16(W + wrow + 64 * 1024 + kt, wsd + 2048);
        __syncthreads();
        short8 af[4], bf_[4];
#pragma unroll
        for (int i = 0; i < 4; i++) af[i] = *(const short8*)&As[(wr * 64 + i * 16 + c) * 32 + g * 8];
#pragma unroll
        for (int j = 0; j < 4; j++) bf_[j] = *(const short8*)&Ws[(wc * 64 + j * 16 + c) * 32 + g * 8];
#pragma unroll
        for (int i = 0; i < 4; i++)
#pragma unroll
            for (int j = 0; j < 4; j++)
                acc[i][j] = MFMA_BF16(af[i], bf_[j], acc[i][j]);
    }

    if (outb) {
#pragma unroll
        for (int i = 0; i < 4; i++)
#pragma unroll
            for (int j = 0; j < 4; j++) {
                int e = n0 + wc * 64 + j * 16 + c;
                float bv = bias[e];
                int hh = e >> 6, d = e & 63;
                int du = d >> 3, dl = d & 7;
#pragma unroll
                for (int ii = 0; ii < 4; ii++) {
                    int m = m0 + wr * 64 + i * 16 + g * 4 + ii;
                    int grp = m >> 9, l = m & 511;
                    int dd = kswz ? ((du ^ (l & 7)) * 8 + dl) : d;
                    outb[(((size_t)grp * 16 + hh) * 512 + l) * 64 + dd] = f2bf(acc[i][j][ii] + bv);
                }
            }
    } else if (outv) {
#pragma unroll
        for (int i = 0; i < 4; i++)
#pragma unroll
            for (int j = 0; j < 4; j++) {
                int e = n0 + wc * 64 + j * 16 + c;
                float bv = bias[e];
                int hh = e >> 6, d = e & 63;
                int mb = m0 + wr * 64 + i * 16 + g * 4;
                int grp = mb >> 9, l = mb & 511;
                ushort4 o;
                o.x = f2bf(acc[i][j][0] + bv);
                o.y = f2bf(acc[i][j][1] + bv);
                o.z = f2bf(acc[i][j][2] + bv);
                o.w = f2bf(acc[i][j][3] + bv);
                *(ushort4*)&outv[(((size_t)grp * 16 + hh) * 64 + d) * 512 + l] = o;
            }
    } else {
#pragma unroll
        for (int i = 0; i < 4; i++)
#pragma unroll
            for (int j = 0; j < 4; j++) {
                int e = n0 + wc * 64 + j * 16 + c;
                float bv = bias[e];
#pragma unroll
                for (int ii = 0; ii < 4; ii++) {
                    int m = m0 + wr * 64 + i * 16 + g * 4 + ii;
                    outf[(size_t)m * 1024 + e] = acc[i][j][ii] + bv + resid[(size_t)m * 1024 + e];
                }
            }
    }
}

// ---------------------------------------------------------------- attention
// 1-D grid 2048, XCD-aware decode: all 8 l-tiles of one (h,bk) on one XCD.
// 4 waves, wave w owns q-rows [w*16, w*16+16).
// scores[l,r] = (q.k + q.E[l-r+511] + k.E[l-r+511]) / 8 + mask[bk,r]
// No-max softmax (scores bounded): P = exp(sc), per-lane partial sum,
// one cross-lane reduce at finalize. QD/KD bands in f32 LDS (no converts).
// K and dist staged via global_load_lds from pre-swizzled global layouts.
__global__ __launch_bounds__(256) void attn_kernel(
    const unsigned short* __restrict__ Qb,   // [4][16][512][64] linear
    const unsigned short* __restrict__ Kbs,  // [16][16][512][64] unit-swizzled
    const unsigned short* __restrict__ Vtb,  // [16][16][64][512] d-major
    const unsigned short* __restrict__ dists,// [1024][64] unit-swizzled
    const float* __restrict__ mask,          // [16][512]
    unsigned short* __restrict__ ctxb)       // [16][512][1024] bf16
{
    // XCD-aware decode
    const int dspt = blockIdx.x;
    const int xcd = dspt & 7, idx = dspt >> 3;
    const int pair = xcd * 32 + (idx >> 3);
    const int lt = idx & 7;
    const int h = pair >> 4, bk = pair & 15;
    const int l0 = lt * 64;
    const int b = bk >> 2;                   // repeat_interleave(q, 4)

    extern __shared__ unsigned char smem[];
    unsigned short* KsU = (unsigned short*)smem;            // [64][64] swizzled units, 8 KB
    unsigned short* DsU = (unsigned short*)(smem + 8192);   // [128][64] swizzled units, 16 KB
    float* QDcf = (float*)(smem + 24576);                   // [64][80] f32 band, 20 KB
    float* KDcf = (float*)(smem + 45056);                   // [64][80] f32 band, 20 KB
    unsigned short* Ps = DsU;                               // alias: [64][72] bf16 probs

    const int t = threadIdx.x, lane = t & 63, w = t >> 6;
    const int c = lane & 15, g = lane >> 4;
    const int xsw  = (g ^ (c & 7)) * 8;          // swizzled elem offset, unit g
    const int xsw4 = ((g + 4) ^ (c & 7)) * 8;    // unit g+4

    const unsigned short* Qg = Qb  + ((size_t)(b  * 16 + h) * 512) * 64;
    const unsigned short* Kg = Kbs + ((size_t)(bk * 16 + h) * 512) * 64;
    const unsigned short* Vg = Vtb + ((size_t)(bk * 16 + h) * 64) * 512;

    // Q fragments hoisted (linear layout)
    short8 aq0 = *(const short8*)&Qg[(size_t)(l0 + w * 16 + c) * 64 + g * 8];
    short8 aq1 = *(const short8*)&Qg[(size_t)(l0 + w * 16 + c) * 64 + 32 + g * 8];

    float s_part[4];
    f32x4 acc_o[4];
#pragma unroll
    for (int i = 0; i < 4; i++) { s_part[i] = 0.f; acc_o[i] = (f32x4)0.f; }

    for (int r0 = 0; r0 < 512; r0 += 64) {
        const int pbase = l0 - r0 + 448;        // dist window start in [0, 896]
        __syncthreads();                        // (1) prev-iteration LDS reads done

        // stage K (2 glls) + dist window (4 glls); linear copy of swizzled global
        GLL16(Kg + (size_t)(r0 + w * 16) * 64 + lane * 8,     KsU + (w * 16) * 64 + lane * 8);
        GLL16(Kg + (size_t)(r0 + w * 16 + 8) * 64 + lane * 8, KsU + (w * 16 + 8) * 64 + lane * 8);
        const unsigned short* dsrc = dists + (size_t)pbase * 64;
#pragma unroll
        for (int j = 0; j < 4; j++)
            GLL16(dsrc + (size_t)(w * 32 + j * 8) * 64 + lane * 8,
                  DsU + (w * 32 + j * 8) * 64 + lane * 8);
        __syncthreads();                        // (2) staging visible (vmcnt drained)

        // issue V + mask loads now; consumed after barrier (3) — latency hidden
        short8 vfr[4][2];
#pragma unroll
        for (int n = 0; n < 4; n++)
#pragma unroll
            for (int j = 0; j < 2; j++)
                vfr[n][j] = *(const short8*)&Vg[(size_t)(n * 16 + c) * 512 + r0 + j * 32 + g * 8];
        const float* mrow = mask + (size_t)bk * 512 + r0;
        float mv_[4];
#pragma unroll
        for (int f = 0; f < 4; f++) mv_[f] = mrow[f * 16 + c];

        // S1 = Q K^T; K B-frags cached (also KD's A-operand)
        short8 bkf0[4], bkf1[4];
        f32x4 s_acc[4];
#pragma unroll
        for (int f = 0; f < 4; f++) {
            bkf0[f] = *(const short8*)&KsU[(f * 16 + c) * 64 + xsw];
            bkf1[f] = *(const short8*)&KsU[(f * 16 + c) * 64 + xsw4];
            f32x4 z = (f32x4)0.f;
            z = MFMA_BF16(aq0, bkf0[f], z);
            s_acc[f] = MFMA_BF16(aq1, bkf1[f], z);
        }
        // QD/KD bands: 5 p-frags per wave, f32 stores (no converts)
#pragma unroll
        for (int q5 = 0; q5 < 5; q5++) {
            const int pq = w + q5;              // QD frags [w, w+4]
            short8 dq0 = *(const short8*)&DsU[(pq * 16 + c) * 64 + xsw];
            short8 dq1 = *(const short8*)&DsU[(pq * 16 + c) * 64 + xsw4];
            f32x4 aQ = (f32x4)0.f;
            aQ = MFMA_BF16(aq0, dq0, aQ);
            aQ = MFMA_BF16(aq1, dq1, aQ);
            const int pk = (3 - w) + q5;        // KD frags [3-w, 7-w]
            short8 dk0 = *(const short8*)&DsU[(pk * 16 + c) * 64 + xsw];
            short8 dk1 = *(const short8*)&DsU[(pk * 16 + c) * 64 + xsw4];
            f32x4 aK = (f32x4)0.f;
            aK = MFMA_BF16(bkf0[w], dk0, aK);
            aK = MFMA_BF16(bkf1[w], dk1, aK);
#pragma unroll
            for (int i = 0; i < 4; i++) {
                QDcf[(w * 16 + g * 4 + i) * 80 + q5 * 16 + c] = aQ[i];
                KDcf[(w * 16 + g * 4 + i) * 80 + q5 * 16 + c] = aK[i];
            }
        }
        __syncthreads();                        // (3) bands visible (also drains V/mask)

        // assemble + exp (no max subtraction; scores bounded) + P store
        float pv_[4][4];
#pragma unroll
        for (int f = 0; f < 4; f++) {
            const float mv2 = mv_[f] * 1.44269504f;
#pragma unroll
            for (int i = 0; i < 4; i++) {
                const int lloc = g * 4 + i;
                float qd = QDcf[(w * 16 + lloc) * 80 + lloc - 16 * f - c + 63];
                float kd = KDcf[(16 * f + c) * 80 + 16 * w + lloc - c + 15];
                float sc = (s_acc[f][i] + qd + kd) * 0.18033688f + mv2;  // *(1/8)*log2e
                float pe = exp2_fast(sc);
                pv_[f][i] = pe;
                s_part[i] += pe;
            }
        }
#pragma unroll
        for (int f = 0; f < 4; f += 2)
#pragma unroll
            for (int i = 0; i < 4; i++) {
                unsigned pk2 = cvt_pk_bf16(pv_[f][i], pv_[f + 1][i]);
                const int row = (w * 16 + g * 4 + i) * 72;
                Ps[row + f * 16 + c] = (unsigned short)pk2;
                Ps[row + (f + 1) * 16 + c] = (unsigned short)(pk2 >> 16);
            }

        // O += P V (P rows wave-local; V from registers)
#pragma unroll
        for (int j = 0; j < 2; j++) {
            short8 ap = *(const short8*)&Ps[(w * 16 + c) * 72 + j * 32 + g * 8];
#pragma unroll
            for (int n = 0; n < 4; n++)
                acc_o[n] = MFMA_BF16(ap, vfr[n][j], acc_o[n]);
        }
    }

    // finalize: one cross-lane sum reduce, then ctx[bk][l][h*64+d] = O/s
#pragma unroll
    for (int off = 1; off < 16; off <<= 1)
#pragma unroll
        for (int i = 0; i < 4; i++) s_part[i] += __shfl_xor(s_part[i], off);
#pragma unroll
    for (int i = 0; i < 4; i++) {
        float inv = 1.0f / s_part[i];
        int ll = w * 16 + g * 4 + i;
        unsigned short* dst = ctxb + ((size_t)bk * 512 + l0 + ll) * 1024 + h * 64;
#pragma unroll
        for (int n = 0; n < 4; n++) dst[n * 16 + c] = f2bf(acc_o[n][i] * inv);
    }
}

// ---------------------------------------------------------------- average over k (bf16)
__global__ void avg_kernel(const unsigned short* __restrict__ ctx, unsigned short* __restrict__ avgb) {
    int i = blockIdx.x * 256 + threadIdx.x;     // ushort4 index over [2048][256]
    if (i >= 2048 * 256) return;
    int e4 = i & 255, bl = i >> 8;
    int b = bl >> 9, l = bl & 511;
    size_t base = ((size_t)(b * 4) * 512 + l) * 256 + e4;
    const ushort4* cv = (const ushort4*)ctx;
    float s0 = 0.f, s1 = 0.f, s2 = 0.f, s3 = 0.f;
#pragma unroll
    for (int j = 0; j < 4; j++) {
        ushort4 v = cv[base + (size_t)j * 512 * 256];
        s0 += bf2f(v.x); s1 += bf2f(v.y); s2 += bf2f(v.z); s3 += bf2f(v.w);
    }
    ushort4 o;
    o.x = f2bf(s0 * 0.25f); o.y = f2bf(s1 * 0.25f);
    o.z = f2bf(s2 * 0.25f); o.w = f2bf(s3 * 0.25f);
    ((ushort4*)avgb)[i] = o;
}

// ---------------------------------------------------------------- LayerNorm rows of 1024 (in-place)
__global__ __launch_bounds__(256) void ln_kernel(float* __restrict__ x,
                                                 const float* __restrict__ gamma,
                                                 const float* __restrict__ beta) {
    const int row = blockIdx.x, t = threadIdx.x;
    float* xr = x + (size_t)row * 1024;
    float v[4], s = 0.f, sq = 0.f;
#pragma unroll
    for (int j = 0; j < 4; j++) { v[j] = xr[t + j * 256]; s += v[j]; sq += v[j] * v[j]; }
#pragma unroll
    for (int off = 1; off < 64; off <<= 1) { s += __shfl_xor(s, off); sq += __shfl_xor(sq, off); }
    __shared__ float ss[4], ssq[4];
    if ((t & 63) == 0) { ss[t >> 6] = s; ssq[t >> 6] = sq; }
    __syncthreads();
    s = ss[0] + ss[1] + ss[2] + ss[3];
    sq = ssq[0] + ssq[1] + ssq[2] + ssq[3];
    float mu = s * (1.f / 1024.f);
    float var = fmaxf(sq * (1.f / 1024.f) - mu * mu, 0.f);
    float inv = 1.0f / sqrtf(var + 1e-12f);
#pragma unroll
    for (int j = 0; j < 4; j++) {
        int e = t + j * 256;
        xr[e] = gamma[e] * (v[j] - mu) * inv + beta[e];
    }
}

// ---------------------------------------------------------------- launch
extern "C" void kernel_launch(void* const* d_in, const int* in_sizes, int n_in,
                              void* d_out, int out_size, void* d_ws, size_t ws_size,
                              hipStream_t stream) {
    const float* hs    = (const float*)d_in[0];
    const float* inj   = (const float*)d_in[1];
    const float* maskp = (const float*)d_in[2];
    const float* Wq    = (const float*)d_in[3];
    const float* bq    = (const float*)d_in[4];
    const float* Wk    = (const float*)d_in[5];
    const float* bk_   = (const float*)d_in[6];
    const float* Wv    = (const float*)d_in[7];
    const float* bv    = (const float*)d_in[8];
    const float* de    = (const float*)d_in[9];
    const float* Wo    = (const float*)d_in[10];
    const float* bo    = (const float*)d_in[11];
    const float* ln_g  = (const float*)d_in[12];
    const float* ln_b  = (const float*)d_in[13];
    float* out = (float*)d_out;
    (void)in_sizes; (void)n_in; (void)out_size; (void)ws_size;

    unsigned char* p = (unsigned char*)d_ws;
    auto take = [&](size_t bytes) {
        unsigned char* r = p;
        p += (bytes + 255) & ~(size_t)255;
        return r;
    };
    unsigned short* hsb   = (unsigned short*)take(2048ull * 1024 * 2);
    unsigned short* injb  = (unsigned short*)take(8192ull * 1024 * 2);
    unsigned short* Wqb   = (unsigned short*)take(1024ull * 1024 * 2);
    unsigned short* Wkb   = (unsigned short*)take(1024ull * 1024 * 2);
    unsigned short* Wvb   = (unsigned short*)take(1024ull * 1024 * 2);
    unsigned short* Wob   = (unsigned short*)take(1024ull * 1024 * 2);
    unsigned short* dists = (unsigned short*)take(1024ull * 64 * 2);   // row 1023 = pad
    unsigned short* Qbuf  = (unsigned short*)take(4ull * 16 * 512 * 64 * 2);
    unsigned short* Kbufs = (unsigned short*)take(16ull * 16 * 512 * 64 * 2);
    unsigned short* Vtb   = (unsigned short*)take(16ull * 16 * 64 * 512 * 2);
    unsigned short* ctxb  = (unsigned short*)take(16ull * 512 * 1024 * 2);
    unsigned short* avgb  = (unsigned short*)take(2048ull * 1024 * 2);

    // fused f32 -> bf16 converts (entry 6 swizzled)
    CvtArgs ca;
    ca.s[0] = hs;  ca.d[0] = hsb;   ca.n4[0] = 2048 * 256;
    ca.s[1] = inj; ca.d[1] = injb;  ca.n4[1] = 8192 * 256;
    ca.s[2] = Wq;  ca.d[2] = Wqb;   ca.n4[2] = 1024 * 256;
    ca.s[3] = Wk;  ca.d[3] = Wkb;   ca.n4[3] = 1024 * 256;
    ca.s[4] = Wv;  ca.d[4] = Wvb;   ca.n4[4] = 1024 * 256;
    ca.s[5] = Wo;  ca.d[5] = Wob;   ca.n4[5] = 1024 * 256;
    ca.s[6] = de;  ca.d[6] = dists; ca.n4[6] = 1023 * 16;
    cvt_all<<<2048, 256, 0, stream>>>(ca);

    // projections (K written unit-swizzled for attn's global_load_lds)
    dim3 gq(16, 8), gkv(64, 8);
    gemm128<<<gq,  256, 0, stream>>>(hsb,  Wqb, bq,  nullptr, Qbuf,  nullptr, nullptr, 0);
    gemm128<<<gkv, 256, 0, stream>>>(injb, Wkb, bk_, nullptr, Kbufs, nullptr, nullptr, 1);
    gemm128<<<gkv, 256, 0, stream>>>(injb, Wvb, bv,  nullptr, nullptr, Vtb,   nullptr, 0);

    // attention (dynamic LDS 64 KB -> 2 WG/CU)
    hipFuncSetAttribute((const void*)attn_kernel,
                        hipFuncAttributeMaxDynamicSharedMemorySize, 131072);
    attn_kernel<<<2048, 256, 65536, stream>>>(Qbuf, Kbufs, Vtb, dists, maskp, ctxb);

    // average over k candidates
    avg_kernel<<<2048, 256, 0, stream>>>(ctxb, avgb);

    // output projection + bias + residual, then LayerNorm in-place on d_out
    gemm128<<<gq, 256, 0, stream>>>(avgb, Wob, bo, hs, nullptr, nullptr, out, 0);
    ln_kernel<<<2048, 256, 0, stream>>>(out, ln_g, ln_b);
}

// Round 4
// 207.712 us; speedup vs baseline: 1.8358x; 1.2965x over previous
//
#include <hip/hip_runtime.h>
#include <hip/hip_bf16.h>
#include <math.h>

// B=4, K=4, L=512, H=16, D=64, HID=1024, MAXPOS=512

typedef __attribute__((ext_vector_type(8))) short short8;
typedef __attribute__((ext_vector_type(4))) float f32x4;

#define MFMA_BF16(a,b,c) __builtin_amdgcn_mfma_f32_16x16x32_bf16((a),(b),(c),0,0,0)
#define GLL16(gp, lp) __builtin_amdgcn_global_load_lds( \
    (const __attribute__((address_space(1))) void*)(gp), \
    (__attribute__((address_space(3))) void*)(lp), 16, 0, 0)

#define SQRT_BETA 0.4246608995262131f   // sqrt(log2(e)/8)
#define LOG2E     1.4426950408889634f

static __device__ __forceinline__ unsigned short f2bf(float x) {
    unsigned int u = __builtin_bit_cast(unsigned int, x);
    u += 0x7fffu + ((u >> 16) & 1u);     // round-to-nearest-even
    return (unsigned short)(u >> 16);
}
static __device__ __forceinline__ float bf2f(unsigned short u) {
    unsigned int v = ((unsigned int)u) << 16;
    return __builtin_bit_cast(float, v);
}
static __device__ __forceinline__ unsigned cvt_pk_bf16(float lo, float hi) {
    unsigned r;
    asm("v_cvt_pk_bf16_f32 %0, %1, %2" : "=v"(r) : "v"(lo), "v"(hi));
    return r;
}
static __device__ __forceinline__ float exp2_fast(float x) {
    float r;
    asm("v_exp_f32 %0, %1" : "=v"(r) : "v"(x));
    return r;
}

// ---------------------------------------------------------------- fused converts
// entry 6 (dist_emb): XOR-swizzled 16B-unit order + pre-scaled by sqrt(beta).
struct CvtArgs {
    const float* s[7];
    unsigned short* d[7];
    int n4[7];
    float scale[7];
};
__global__ void cvt_all(CvtArgs a) {
#pragma unroll 1
    for (int k = 0; k < 7; k++) {
        const float4* s = (const float4*)a.s[k];
        ushort4* d = (ushort4*)a.d[k];
        const int n = a.n4[k];
        const float sc = a.scale[k];
        const bool swz = (k == 6);
        for (int i = blockIdx.x * 256 + threadIdx.x; i < n; i += gridDim.x * 256) {
            float4 v = s[i];
            ushort4 o;
            o.x = f2bf(v.x * sc); o.y = f2bf(v.y * sc);
            o.z = f2bf(v.z * sc); o.w = f2bf(v.w * sc);
            int di = i;
            if (swz) {
                int p = i >> 4, j = i & 15;
                di = p * 16 + (((j >> 1) ^ (p & 7)) * 2 + (j & 1));
            }
            d[di] = o;
        }
    }
}

// ---------------------------------------------------------------- GEMM 128x128, BK=32 (m97 structure)
// C[m,e] = (sum_d A[m,d]*W[e,d] + bias[e]) * scale.
__global__ __launch_bounds__(256) void gemm128(
    const unsigned short* __restrict__ A,
    const unsigned short* __restrict__ W,
    const float* __restrict__ bias,
    const float* __restrict__ resid,
    unsigned short* __restrict__ outb,
    unsigned short* __restrict__ outv,
    float* __restrict__ outf,
    int kswz, float scale)
{
    const int m0 = blockIdx.x * 128, n0 = blockIdx.y * 128;
    __shared__ unsigned short As[128 * 32];
    __shared__ unsigned short Ws[128 * 32];
    const int t = threadIdx.x, lane = t & 63, w = t >> 6;
    const int wr = w >> 1, wc = w & 1;
    const int c = lane & 15, g = lane >> 4;

    f32x4 acc[4][4];
#pragma unroll
    for (int i = 0; i < 4; i++)
#pragma unroll
        for (int j = 0; j < 4; j++) acc[i][j] = (f32x4)0.f;

    const size_t arow = (size_t)(m0 + (t >> 2)) * 1024 + (size_t)((t & 3) * 8);
    const size_t wrow = (size_t)(n0 + (t >> 2)) * 1024 + (size_t)((t & 3) * 8);
    unsigned short* asd = As + t * 8;
    unsigned short* wsd = Ws + t * 8;

    for (int kt = 0; kt < 1024; kt += 32) {
        __syncthreads();
        GLL16(A + arow + kt, asd);
        GLL16(A + arow + 64 * 1024 + kt, asd + 2048);
        GLL16(W + wrow + kt, wsd);
        GLL16(W + wrow + 64 * 1024 + kt, wsd + 2048);
        __syncthreads();
        short8 af[4], bf_[4];
#pragma unroll
        for (int i = 0; i < 4; i++) af[i] = *(const short8*)&As[(wr * 64 + i * 16 + c) * 32 + g * 8];
#pragma unroll
        for (int j = 0; j < 4; j++) bf_[j] = *(const short8*)&Ws[(wc * 64 + j * 16 + c) * 32 + g * 8];
#pragma unroll
        for (int i = 0; i < 4; i++)
#pragma unroll
            for (int j = 0; j < 4; j++)
                acc[i][j] = MFMA_BF16(af[i], bf_[j], acc[i][j]);
    }

    if (outb) {
#pragma unroll
        for (int i = 0; i < 4; i++)
#pragma unroll
            for (int j = 0; j < 4; j++) {
                int e = n0 + wc * 64 + j * 16 + c;
                float bv = bias[e];
                int hh = e >> 6, d = e & 63;
                int du = d >> 3, dl = d & 7;
#pragma unroll
                for (int ii = 0; ii < 4; ii++) {
                    int m = m0 + wr * 64 + i * 16 + g * 4 + ii;
                    int grp = m >> 9, l = m & 511;
                    int dd = kswz ? ((du ^ (l & 7)) * 8 + dl) : d;
                    outb[(((size_t)grp * 16 + hh) * 512 + l) * 64 + dd] = f2bf((acc[i][j][ii] + bv) * scale);
                }
            }
    } else if (outv) {
#pragma unroll
        for (int i = 0; i < 4; i++)
#pragma unroll
            for (int j = 0; j < 4; j++) {
                int e = n0 + wc * 64 + j * 16 + c;
                float bv = bias[e];
                int hh = e >> 6, d = e & 63;
                int mb = m0 + wr * 64 + i * 16 + g * 4;
                int grp = mb >> 9, l = mb & 511;
                ushort4 o;
                o.x = f2bf(acc[i][j][0] + bv);
                o.y = f2bf(acc[i][j][1] + bv);
                o.z = f2bf(acc[i][j][2] + bv);
                o.w = f2bf(acc[i][j][3] + bv);
                *(ushort4*)&outv[(((size_t)grp * 16 + hh) * 64 + d) * 512 + l] = o;
            }
    } else {
#pragma unroll
        for (int i = 0; i < 4; i++)
#pragma unroll
            for (int j = 0; j < 4; j++) {
                int e = n0 + wc * 64 + j * 16 + c;
                float bv = bias[e];
#pragma unroll
                for (int ii = 0; ii < 4; ii++) {
                    int m = m0 + wr * 64 + i * 16 + g * 4 + ii;
                    outf[(size_t)m * 1024 + e] = acc[i][j][ii] + bv + resid[(size_t)m * 1024 + e];
                }
            }
    }
}

// ---------------------------------------------------------------- attention
// 1-D grid 2048, XCD-aware decode. 4 waves; wave w owns q-rows [w*16,w*16+16).
// Q,K,E pre-scaled by sqrt(beta), beta=log2e/8 -> each score term carries beta.
// Mask folded into S1 accumulator init. QD gathered via ds_bpermute (no LDS).
// KD computed transposed (E rows as A) -> b128 band writes; each wave reads
// only its own band columns (no sync needed). KDs aliases KsU/DsU after the
// post-read barrier. LDS = 33.5 KB -> 3 WG/CU.
__global__ __launch_bounds__(256, 3) void attn_kernel(
    const unsigned short* __restrict__ Qb,   // [4][16][512][64] linear, *sqrt(beta)
    const unsigned short* __restrict__ Kbs,  // [16][16][512][64] unit-swizzled, *sqrt(beta)
    const unsigned short* __restrict__ Vtb,  // [16][16][64][512] d-major
    const unsigned short* __restrict__ dists,// [1024][64] unit-swizzled, *sqrt(beta)
    const float* __restrict__ mask,          // [16][512]
    unsigned short* __restrict__ ctxb)       // [16][512][1024] bf16
{
    // XCD-aware decode: all 8 l-tiles of one (h,bk) on one XCD
    const int dspt = blockIdx.x;
    const int xcd = dspt & 7, idx = dspt >> 3;
    const int pair = xcd * 32 + (idx >> 3);
    const int lt = idx & 7;
    const int h = pair >> 4, bk = pair & 15;
    const int l0 = lt * 64;
    const int b = bk >> 2;                   // repeat_interleave(q, 4)

    __shared__ unsigned char smem[34304];
    unsigned short* KsU = (unsigned short*)smem;            // [64][64] swizzled units
    unsigned short* DsU = (unsigned short*)(smem + 8192);   // [128][64] swizzled units
    float* KDs = (float*)smem;                              // [64][84] f32 band (alias!)
    unsigned short* Ps = (unsigned short*)(smem + 24576);   // [64][76] bf16 probs

    const int t = threadIdx.x, lane = t & 63, w = t >> 6;
    const int c = lane & 15, g = lane >> 4;
    const int xsw  = (g ^ (c & 7)) * 8;          // swizzled elem offset, unit g
    const int xsw4 = ((g + 4) ^ (c & 7)) * 8;    // unit g+4

    const unsigned short* Qg = Qb  + ((size_t)(b  * 16 + h) * 512) * 64;
    const unsigned short* Kg = Kbs + ((size_t)(bk * 16 + h) * 512) * 64;
    const unsigned short* Vg = Vtb + ((size_t)(bk * 16 + h) * 64) * 512;

    // Q fragments hoisted (linear layout, pre-scaled)
    short8 aq0 = *(const short8*)&Qg[(size_t)(l0 + w * 16 + c) * 64 + g * 8];
    short8 aq1 = *(const short8*)&Qg[(size_t)(l0 + w * 16 + c) * 64 + 32 + g * 8];

    // QD-gather constants (tile-invariant)
    int bpa[4];
    bool selb[4];
#pragma unroll
    for (int i = 0; i < 4; i++) {
        int cp = (g * 4 + i - c + 15) & 15;
        bpa[i] = (g * 16 + cp) * 4;
        selb[i] = (g * 4 + i) > c;
    }

    float s_part[4];
    f32x4 acc_o[4];
#pragma unroll
    for (int i = 0; i < 4; i++) { s_part[i] = 0.f; acc_o[i] = (f32x4)0.f; }

    for (int r0 = 0; r0 < 512; r0 += 64) {
        const int pbase = l0 - r0 + 448;        // dist window start in [0, 896]
        __syncthreads();                        // (1) prev-tile LDS reads done

        // stage K (2 glls) + dist window (4 glls)
        GLL16(Kg + (size_t)(r0 + w * 16) * 64 + lane * 8,     KsU + (w * 16) * 64 + lane * 8);
        GLL16(Kg + (size_t)(r0 + w * 16 + 8) * 64 + lane * 8, KsU + (w * 16 + 8) * 64 + lane * 8);
        const unsigned short* dsrc = dists + (size_t)pbase * 64;
#pragma unroll
        for (int j = 0; j < 4; j++)
            GLL16(dsrc + (size_t)(w * 32 + j * 8) * 64 + lane * 8,
                  DsU + (w * 32 + j * 8) * 64 + lane * 8);
        // mask (folded into S1 acc init); drained by barrier(2)'s vmcnt
        const float* mrow = mask + (size_t)bk * 512 + r0;
        float mv2[4];
#pragma unroll
        for (int f = 0; f < 4; f++) mv2[f] = mrow[f * 16 + c] * LOG2E;
        __syncthreads();                        // (2) staging visible

        // fragment reads: K (8 b128) and dist (10 b128)
        short8 bkf0[4], bkf1[4];
#pragma unroll
        for (int f = 0; f < 4; f++) {
            bkf0[f] = *(const short8*)&KsU[(f * 16 + c) * 64 + xsw];
            bkf1[f] = *(const short8*)&KsU[(f * 16 + c) * 64 + xsw4];
        }
        short8 dq0[5], dq1[5];
#pragma unroll
        for (int q5 = 0; q5 < 5; q5++) {
            dq0[q5] = *(const short8*)&DsU[((w + q5) * 16 + c) * 64 + xsw];
            dq1[q5] = *(const short8*)&DsU[((w + q5) * 16 + c) * 64 + xsw4];
        }
        __syncthreads();                        // (2b) all LDS reads done -> KDs alias safe

        // S1 = QK^T with mask-init accumulator
        f32x4 s_acc[4];
#pragma unroll
        for (int f = 0; f < 4; f++) {
            f32x4 z = {mv2[f], mv2[f], mv2[f], mv2[f]};
            z = MFMA_BF16(aq0, bkf0[f], z);
            s_acc[f] = MFMA_BF16(aq1, bkf1[f], z);
        }
        // QD: 5 frags, stays in registers
        f32x4 aQ[5];
#pragma unroll
        for (int q5 = 0; q5 < 5; q5++) {
            f32x4 z = (f32x4)0.f;
            z = MFMA_BF16(aq0, dq0[q5], z);
            aQ[q5] = MFMA_BF16(aq1, dq1[q5], z);
        }
        // KD transposed: buckets {w, w+1}, b128 band writes; own-wave read coverage
#pragma unroll
        for (int f = 0; f < 4; f++)
#pragma unroll
            for (int pk = 0; pk < 2; pk++) {
                f32x4 aK = (f32x4)0.f;
                aK = MFMA_BF16(dq0[pk], bkf0[f], aK);
                aK = MFMA_BF16(dq1[pk], bkf1[f], aK);
                *(f32x4*)&KDs[(16 * f + c) * 84 + (w + pk) * 16 + g * 4] = aK;
            }

        // issue V loads (consumed in PV after assembly -> latency hidden)
        short8 vfr[4][2];
#pragma unroll
        for (int n = 0; n < 4; n++)
#pragma unroll
            for (int j = 0; j < 2; j++)
                vfr[n][j] = *(const short8*)&Vg[(size_t)(n * 16 + c) * 512 + r0 + j * 32 + g * 8];

        // QD gather: 20 bpermute + 16 cndmask
        int bp[5][4];
#pragma unroll
        for (int q5 = 0; q5 < 5; q5++)
#pragma unroll
            for (int i = 0; i < 4; i++)
                bp[q5][i] = __builtin_amdgcn_ds_bpermute(bpa[i], __builtin_bit_cast(int, aQ[q5][i]));

        // assembly: exp2(s1 + qd + kd), accumulate denom
        float pv[4][4];
#pragma unroll
        for (int f = 0; f < 4; f++) {
            const float* kdb = &KDs[(16 * f + c) * 84 + w * 16 + g * 4 - c + 15];
#pragma unroll
            for (int i = 0; i < 4; i++) {
                float kd = kdb[i];
                float qd = __builtin_bit_cast(float, selb[i] ? bp[4 - f][i] : bp[3 - f][i]);
                float pe = exp2_fast(s_acc[f][i] + qd + kd);
                pv[f][i] = pe;
                s_part[i] += pe;
            }
        }
        // P -> LDS (own rows; no barrier needed before PV)
#pragma unroll
        for (int f = 0; f < 4; f += 2)
#pragma unroll
            for (int i = 0; i < 4; i++) {
                unsigned pk2 = cvt_pk_bf16(pv[f][i], pv[f + 1][i]);
                const int row = (w * 16 + g * 4 + i) * 76;
                Ps[row + f * 16 + c] = (unsigned short)pk2;
                Ps[row + (f + 1) * 16 + c] = (unsigned short)(pk2 >> 16);
            }

        // O += P V
#pragma unroll
        for (int j = 0; j < 2; j++) {
            short8 ap = *(const short8*)&Ps[(w * 16 + c) * 76 + j * 32 + g * 8];
#pragma unroll
            for (int n = 0; n < 4; n++)
                acc_o[n] = MFMA_BF16(ap, vfr[n][j], acc_o[n]);
        }
    }

    // finalize: cross-lane denom reduce, then ctx[bk][l][h*64+d] = O/s
#pragma unroll
    for (int off = 1; off < 16; off <<= 1)
#pragma unroll
        for (int i = 0; i < 4; i++) s_part[i] += __shfl_xor(s_part[i], off);
#pragma unroll
    for (int i = 0; i < 4; i++) {
        float inv = 1.0f / s_part[i];
        int ll = w * 16 + g * 4 + i;
        unsigned short* dst = ctxb + ((size_t)bk * 512 + l0 + ll) * 1024 + h * 64;
#pragma unroll
        for (int n = 0; n < 4; n++) dst[n * 16 + c] = f2bf(acc_o[n][i] * inv);
    }
}

// ---------------------------------------------------------------- average over k (bf16)
__global__ void avg_kernel(const unsigned short* __restrict__ ctx, unsigned short* __restrict__ avgb) {
    int i = blockIdx.x * 256 + threadIdx.x;     // ushort4 index over [2048][256]
    if (i >= 2048 * 256) return;
    int e4 = i & 255, bl = i >> 8;
    int b = bl >> 9, l = bl & 511;
    size_t base = ((size_t)(b * 4) * 512 + l) * 256 + e4;
    const ushort4* cv = (const ushort4*)ctx;
    float s0 = 0.f, s1 = 0.f, s2 = 0.f, s3 = 0.f;
#pragma unroll
    for (int j = 0; j < 4; j++) {
        ushort4 v = cv[base + (size_t)j * 512 * 256];
        s0 += bf2f(v.x); s1 += bf2f(v.y); s2 += bf2f(v.z); s3 += bf2f(v.w);
    }
    ushort4 o;
    o.x = f2bf(s0 * 0.25f); o.y = f2bf(s1 * 0.25f);
    o.z = f2bf(s2 * 0.25f); o.w = f2bf(s3 * 0.25f);
    ((ushort4*)avgb)[i] = o;
}

// ---------------------------------------------------------------- LayerNorm rows of 1024 (in-place)
__global__ __launch_bounds__(256) void ln_kernel(float* __restrict__ x,
                                                 const float* __restrict__ gamma,
                                                 const float* __restrict__ beta) {
    const int row = blockIdx.x, t = threadIdx.x;
    float* xr = x + (size_t)row * 1024;
    float v[4], s = 0.f, sq = 0.f;
#pragma unroll
    for (int j = 0; j < 4; j++) { v[j] = xr[t + j * 256]; s += v[j]; sq += v[j] * v[j]; }
#pragma unroll
    for (int off = 1; off < 64; off <<= 1) { s += __shfl_xor(s, off); sq += __shfl_xor(sq, off); }
    __shared__ float ss[4], ssq[4];
    if ((t & 63) == 0) { ss[t >> 6] = s; ssq[t >> 6] = sq; }
    __syncthreads();
    s = ss[0] + ss[1] + ss[2] + ss[3];
    sq = ssq[0] + ssq[1] + ssq[2] + ssq[3];
    float mu = s * (1.f / 1024.f);
    float var = fmaxf(sq * (1.f / 1024.f) - mu * mu, 0.f);
    float inv = 1.0f / sqrtf(var + 1e-12f);
#pragma unroll
    for (int j = 0; j < 4; j++) {
        int e = t + j * 256;
        xr[e] = gamma[e] * (v[j] - mu) * inv + beta[e];
    }
}

// ---------------------------------------------------------------- launch
extern "C" void kernel_launch(void* const* d_in, const int* in_sizes, int n_in,
                              void* d_out, int out_size, void* d_ws, size_t ws_size,
                              hipStream_t stream) {
    const float* hs    = (const float*)d_in[0];
    const float* inj   = (const float*)d_in[1];
    const float* maskp = (const float*)d_in[2];
    const float* Wq    = (const float*)d_in[3];
    const float* bq    = (const float*)d_in[4];
    const float* Wk    = (const float*)d_in[5];
    const float* bk_   = (const float*)d_in[6];
    const float* Wv    = (const float*)d_in[7];
    const float* bv    = (const float*)d_in[8];
    const float* de    = (const float*)d_in[9];
    const float* Wo    = (const float*)d_in[10];
    const float* bo    = (const float*)d_in[11];
    const float* ln_g  = (const float*)d_in[12];
    const float* ln_b  = (const float*)d_in[13];
    float* out = (float*)d_out;
    (void)in_sizes; (void)n_in; (void)out_size; (void)ws_size;

    unsigned char* p = (unsigned char*)d_ws;
    auto take = [&](size_t bytes) {
        unsigned char* r = p;
        p += (bytes + 255) & ~(size_t)255;
        return r;
    };
    unsigned short* hsb   = (unsigned short*)take(2048ull * 1024 * 2);
    unsigned short* injb  = (unsigned short*)take(8192ull * 1024 * 2);
    unsigned short* Wqb   = (unsigned short*)take(1024ull * 1024 * 2);
    unsigned short* Wkb   = (unsigned short*)take(1024ull * 1024 * 2);
    unsigned short* Wvb   = (unsigned short*)take(1024ull * 1024 * 2);
    unsigned short* Wob   = (unsigned short*)take(1024ull * 1024 * 2);
    unsigned short* dists = (unsigned short*)take(1024ull * 64 * 2);   // row 1023 = pad
    unsigned short* Qbuf  = (unsigned short*)take(4ull * 16 * 512 * 64 * 2);
    unsigned short* Kbufs = (unsigned short*)take(16ull * 16 * 512 * 64 * 2);
    unsigned short* Vtb   = (unsigned short*)take(16ull * 16 * 64 * 512 * 2);
    unsigned short* ctxb  = (unsigned short*)take(16ull * 512 * 1024 * 2);
    unsigned short* avgb  = (unsigned short*)take(2048ull * 1024 * 2);

    // fused f32 -> bf16 converts (entry 6 swizzled + sqrt(beta)-scaled)
    CvtArgs ca;
    ca.s[0] = hs;  ca.d[0] = hsb;   ca.n4[0] = 2048 * 256; ca.scale[0] = 1.f;
    ca.s[1] = inj; ca.d[1] = injb;  ca.n4[1] = 8192 * 256; ca.scale[1] = 1.f;
    ca.s[2] = Wq;  ca.d[2] = Wqb;   ca.n4[2] = 1024 * 256; ca.scale[2] = 1.f;
    ca.s[3] = Wk;  ca.d[3] = Wkb;   ca.n4[3] = 1024 * 256; ca.scale[3] = 1.f;
    ca.s[4] = Wv;  ca.d[4] = Wvb;   ca.n4[4] = 1024 * 256; ca.scale[4] = 1.f;
    ca.s[5] = Wo;  ca.d[5] = Wob;   ca.n4[5] = 1024 * 256; ca.scale[5] = 1.f;
    ca.s[6] = de;  ca.d[6] = dists; ca.n4[6] = 1023 * 16;  ca.scale[6] = SQRT_BETA;
    cvt_all<<<2048, 256, 0, stream>>>(ca);

    // projections (Q,K scaled by sqrt(beta); K unit-swizzled for attn GLL)
    dim3 gq(16, 8), gkv(64, 8);
    gemm128<<<gq,  256, 0, stream>>>(hsb,  Wqb, bq,  nullptr, Qbuf,  nullptr, nullptr, 0, SQRT_BETA);
    gemm128<<<gkv, 256, 0, stream>>>(injb, Wkb, bk_, nullptr, Kbufs, nullptr, nullptr, 1, SQRT_BETA);
    gemm128<<<gkv, 256, 0, stream>>>(injb, Wvb, bv,  nullptr, nullptr, Vtb,   nullptr, 0, 1.f);

    // attention (static LDS 33.5 KB -> 3 WG/CU)
    attn_kernel<<<2048, 256, 0, stream>>>(Qbuf, Kbufs, Vtb, dists, maskp, ctxb);

    // average over k candidates
    avg_kernel<<<2048, 256, 0, stream>>>(ctxb, avgb);

    // output projection + bias + residual, then LayerNorm in-place on d_out
    gemm128<<<gq, 256, 0, stream>>>(avgb, Wob, bo, hs, nullptr, nullptr, out, 0, 1.f);
    ln_kernel<<<2048, 256, 0, stream>>>(out, ln_g, ln_b);
}